// Round 6
// baseline (338.554 us; speedup 1.0000x reference)
//
#include <hip/hip_runtime.h>
#include <cstdint>

#define KT 9408      // K_TOTAL
#define NT 256       // o-tile per block (wfa partial gemm)
#define KC 16        // k sub-chunk staged in LDS

// ---------------------------------------------------------------------------
// One-shot small GEMM: Y[b][o] = bias(+bias2) + sum_k X[b,k]*W[o,k], opt ReLU.
// Dual-source concatenated K (K1 then K2). M=32. Block = 256 thr, o-tile 16.
// The 4 waves split K into quarters (Kq = Ktot/4, caller ensures Kq%16==0);
// each wave stages its own X/W chunks in private LDS (wave-coherent, no
// barriers in the K-loop), then one __syncthreads + LDS cross-wave reduce.
// Eliminates the partial-buffer round trip and the reduce dispatch.
// ---------------------------------------------------------------------------
__global__ __launch_bounds__(256) void smallgemm(
    const float* __restrict__ X1, const float* __restrict__ W1, int K1,
    const float* __restrict__ X2, const float* __restrict__ W2, int K2,
    const float* __restrict__ bias1, const float* __restrict__ bias2,
    float* __restrict__ Y, int O, int relu)
{
    __shared__ float Xs[4][KC][32];   // per-wave [k_local][b]
    __shared__ float Wt[4][KC][16];   // per-wave [k_local][o_local]
    __shared__ float red[4][16][32];  // cross-wave reduce [w][o][b]

    const int t    = threadIdx.x;
    const int lane = t & 63;
    const int w    = t >> 6;
    const int o0   = blockIdx.x * 16;
    const int o_l  = lane & 15;
    const int bg   = lane >> 4;            // b-group: b = 8*bg + bi
    const int Kq   = (K1 + K2) >> 2;       // per-wave K range, %16 == 0
    const int kbeg = w * Kq;
    const int kend = kbeg + Kq;

    const int wr  = lane >> 2;             // W stage: row 0..15
    const int wc4 = (lane & 3) << 2;       // W stage: col 0,4,8,12

    float acc[8];
#pragma unroll
    for (int i = 0; i < 8; ++i) acc[i] = 0.f;

    for (int kc = kbeg; kc < kend; kc += KC) {
        // ---- stage X chunk (transposed) into this wave's buffer
#pragma unroll
        for (int i = 0; i < 8; ++i) {
            int idx = lane + 64 * i;       // 0..511
            int c   = idx >> 5;
            int bb  = idx & 31;
            int kg  = kc + c;
            Xs[w][c][bb] = (kg < K1) ? X1[(size_t)bb * K1 + kg]
                                     : X2[(size_t)bb * K2 + (kg - K1)];
        }
        // ---- stage W chunk (16 rows x 16 k) as one float4 per lane
        {
            int kg = kc + wc4;             // no float4 straddle: K1 % 4 == 0
            float4 v = (kg < K1) ? *(const float4*)&W1[(size_t)(o0 + wr) * K1 + kg]
                                 : *(const float4*)&W2[(size_t)(o0 + wr) * K2 + (kg - K1)];
            Wt[w][wc4 + 0][wr] = v.x;
            Wt[w][wc4 + 1][wr] = v.y;
            Wt[w][wc4 + 2][wr] = v.z;
            Wt[w][wc4 + 3][wr] = v.w;
        }
        // wave-private LDS: compiler's lgkmcnt ordering suffices, no barrier
#pragma unroll
        for (int c = 0; c < KC; ++c) {
            float wv = Wt[w][c][o_l];
            float4 xa = *(const float4*)&Xs[w][c][8 * bg];
            float4 xb = *(const float4*)&Xs[w][c][8 * bg + 4];
            acc[0] += wv * xa.x; acc[1] += wv * xa.y;
            acc[2] += wv * xa.z; acc[3] += wv * xa.w;
            acc[4] += wv * xb.x; acc[5] += wv * xb.y;
            acc[6] += wv * xb.z; acc[7] += wv * xb.w;
        }
    }

    // ---- cross-wave reduce + epilogue
#pragma unroll
    for (int bi = 0; bi < 8; ++bi) red[w][o_l][8 * bg + bi] = acc[bi];
    __syncthreads();

#pragma unroll
    for (int half = 0; half < 2; ++half) {
        int cell = t + 256 * half;         // 0..511 = o*32 + b
        int o = cell >> 5;
        int b = cell & 31;
        float s = red[0][o][b] + red[1][o][b] + red[2][o][b] + red[3][o][b];
        s += bias1[o0 + o] + (bias2 ? bias2[o0 + o] : 0.f);
        if (relu) s = fmaxf(s, 0.f);
        Y[(size_t)b * O + o0 + o] = s;
    }
}

// ---------------------------------------------------------------------------
// Partial GEMM for wfa:  partial[s][b][o] = sum_{k in split s} X[b,k]*W[o,k]
// (structure unchanged from R4; used only for the 9408x9408 layer)
// ---------------------------------------------------------------------------
__global__ __launch_bounds__(256, 1) void gemm32_partial(
    const float* __restrict__ X1, const float* __restrict__ W1, int K1,
    float* __restrict__ partial, int O, int ksplit)
{
    __shared__ float Xs[KC][32];     // [k_local][b]
    __shared__ float Wt[KC][NT];     // [k_local][o_local] transposed

    const int t      = threadIdx.x;
    const int o0     = blockIdx.x * NT;
    const int s      = blockIdx.y;
    const int kchunk = K1 / ksplit;            // multiple of KC
    const int kbeg   = s * kchunk;
    const int kend   = kbeg + kchunk;
    const int lane   = t & 63;
    const int wv     = t >> 6;                 // wave id -> b-group (8 b's)

    const int sr  = t >> 2;                    // 0..63  (+64*p)
    const int sc4 = (t & 3) << 2;              // 0,4,8,12

    float4 wpre[4];
    float  xpre[2];

    {
        int kc0 = kbeg;
#pragma unroll
        for (int p = 0; p < 4; ++p) {
            int r = sr + 64 * p;
            int o = o0 + r;
            float4 v = make_float4(0.f, 0.f, 0.f, 0.f);
            if (o < O) v = *(const float4*)&W1[(size_t)o * K1 + kc0 + sc4];
            wpre[p] = v;
        }
#pragma unroll
        for (int it = 0; it < 2; ++it) {
            int idx = t + 256 * it;
            xpre[it] = X1[(size_t)(idx & 31) * K1 + kc0 + (idx >> 5)];
        }
    }

    float acc[8][4];
#pragma unroll
    for (int bi = 0; bi < 8; bi++)
#pragma unroll
        for (int j = 0; j < 4; j++) acc[bi][j] = 0.f;

    for (int kc0 = kbeg; kc0 < kend; kc0 += KC) {
#pragma unroll
        for (int it = 0; it < 2; ++it) {
            int idx = t + 256 * it;
            Xs[idx >> 5][idx & 31] = xpre[it];
        }
#pragma unroll
        for (int p = 0; p < 4; ++p) {
            int r = sr + 64 * p;
            Wt[sc4 + 0][r] = wpre[p].x;
            Wt[sc4 + 1][r] = wpre[p].y;
            Wt[sc4 + 2][r] = wpre[p].z;
            Wt[sc4 + 3][r] = wpre[p].w;
        }
        __syncthreads();

        if (kc0 + KC < kend) {
            int kn = kc0 + KC;
#pragma unroll
            for (int p = 0; p < 4; ++p) {
                int r = sr + 64 * p;
                int o = o0 + r;
                float4 v = make_float4(0.f, 0.f, 0.f, 0.f);
                if (o < O) v = *(const float4*)&W1[(size_t)o * K1 + kn + sc4];
                wpre[p] = v;
            }
#pragma unroll
            for (int it = 0; it < 2; ++it) {
                int idx = t + 256 * it;
                xpre[it] = X1[(size_t)(idx & 31) * K1 + kn + (idx >> 5)];
            }
        }

#pragma unroll
        for (int c = 0; c < KC; c++) {
            float4 xa = *(const float4*)&Xs[c][wv * 8];       // wave-broadcast
            float4 xb = *(const float4*)&Xs[c][wv * 8 + 4];
            float xv[8] = {xa.x, xa.y, xa.z, xa.w, xb.x, xb.y, xb.z, xb.w};
            float ww[4];
#pragma unroll
            for (int j = 0; j < 4; j++) ww[j] = Wt[c][lane + 64 * j];
#pragma unroll
            for (int bi = 0; bi < 8; bi++)
#pragma unroll
                for (int j = 0; j < 4; j++) acc[bi][j] += xv[bi] * ww[j];
        }
        __syncthreads();
    }

#pragma unroll
    for (int bi = 0; bi < 8; bi++) {
        int b = wv * 8 + bi;
#pragma unroll
        for (int j = 0; j < 4; j++) {
            int o = o0 + lane + 64 * j;
            if (o < O)
                partial[((size_t)s * 32 + b) * O + o] = acc[bi][j];
        }
    }
}

// ---------------------------------------------------------------------------
__global__ __launch_bounds__(256) void reduce_bias(
    const float* __restrict__ partial, const float* __restrict__ bias1,
    float* __restrict__ Y, int O, int ksplit)
{
    int idx = blockIdx.x * 256 + threadIdx.x;
    if (idx >= 32 * O) return;
    int b = idx / O, o = idx - b * O;
    float s = bias1[o];
    for (int k = 0; k < ksplit; k++)
        s += partial[((size_t)k * 32 + b) * O + o];
    Y[idx] = s;
}

// ---------------------------------------------------------------------------
// MFMA conv chain (unchanged from R5). D-frag layout == B-frag layout, so
// each layer's output packs straight into the next layer's B operand.
// ---------------------------------------------------------------------------
typedef __attribute__((ext_vector_type(8))) short bf16x8;
typedef __attribute__((ext_vector_type(4))) float f32x4;

__device__ inline uint32_t pkbf(float lo, float hi) {   // 2 f32 -> packed bf16x2 (RNE)
    uint32_t a = __builtin_bit_cast(uint32_t, lo);
    uint32_t b = __builtin_bit_cast(uint32_t, hi);
    a = (a + 0x7FFFu + ((a >> 16) & 1u)) >> 16;
    b = (b + 0x7FFFu + ((b >> 16) & 1u)) & 0xFFFF0000u;
    return a | b;
}

#define MFMA16(a, b, c) __builtin_amdgcn_mfma_f32_16x16x32_bf16(a, b, c, 0, 0, 0)

#define TPW 16   // pixel tiles (16 px) per wave

__global__ __launch_bounds__(256, 3) void conv_mfma(
    const float* __restrict__ x, const float* __restrict__ ks,
    float* __restrict__ out)
{
    const int t  = threadIdx.x;
    const int b  = blockIdx.y;
    const int l  = t & 63;
    const int g  = l >> 4;         // lane group 0..3
    const int n  = l & 15;         // col (pixel-in-tile) / A row offset
    const int wid = blockIdx.x * 4 + (t >> 6);   // wave id in sample, 0..63

    const float* __restrict__ kb = ks + (size_t)b * KT;

    auto loadA = [&](const float* W, int ldw, int row0, int k0) -> bf16x8 {
        const float* p = W + (size_t)(row0 + n) * ldw + k0 + 4 * g;
        float4 lo = *(const float4*)p;
        float4 hi = *(const float4*)(p + 16);
        union { bf16x8 v; uint32_t u[4]; } r;
        r.u[0] = pkbf(lo.x, lo.y);
        r.u[1] = pkbf(lo.z, lo.w);
        r.u[2] = pkbf(hi.x, hi.y);
        r.u[3] = pkbf(hi.z, hi.w);
        return r.v;
    };
    auto loadBias = [&](int off) -> f32x4 {
        float4 v = *(const float4*)&kb[off + 4 * g];
        f32x4 r; r[0] = v.x; r[1] = v.y; r[2] = v.z; r[3] = v.w;
        return r;
    };

    bf16x8 ain[4], amid[4][2], aout[2][2], ashort[2];
#pragma unroll
    for (int rt = 0; rt < 4; ++rt) ain[rt] = loadA(kb, 32, 16 * rt, 0);
#pragma unroll
    for (int ot = 0; ot < 4; ++ot)
#pragma unroll
        for (int kf = 0; kf < 2; ++kf) amid[ot][kf] = loadA(kb + 2048, 64, 16 * ot, 32 * kf);
#pragma unroll
    for (int ot = 0; ot < 2; ++ot)
#pragma unroll
        for (int kf = 0; kf < 2; ++kf) aout[ot][kf] = loadA(kb + 6144, 64, 16 * ot, 32 * kf);
#pragma unroll
    for (int ot = 0; ot < 2; ++ot) ashort[ot] = loadA(kb + 8192, 32, 16 * ot, 0);

    f32x4 bin[4], bmid[4], bos[2];
#pragma unroll
    for (int rt = 0; rt < 4; ++rt) bin[rt] = loadBias(9216 + 16 * rt);
#pragma unroll
    for (int ot = 0; ot < 4; ++ot) bmid[ot] = loadBias(9280 + 16 * ot);
#pragma unroll
    for (int ot = 0; ot < 2; ++ot) {
        f32x4 a = loadBias(9344 + 16 * ot);   // b_out
        f32x4 c = loadBias(9376 + 16 * ot);   // b_short
#pragma unroll
        for (int r = 0; r < 4; ++r) a[r] += c[r];
        bos[ot] = a;
    }

    const float* __restrict__ xbase = x + (size_t)b * 524288 + (size_t)(4 * g) * 16384 + n;
    float* __restrict__ obase = out + (size_t)b * 524288 + (size_t)(4 * g) * 16384 + n;

#pragma unroll 1
    for (int it = 0; it < TPW; ++it) {
        const int px0 = (wid * TPW + it) * 16;

        const float* p = xbase + px0;
        float e0 = p[0], e1 = p[16384], e2 = p[2 * 16384], e3 = p[3 * 16384];
        const float* q = p + (size_t)16 * 16384;
        float e4 = q[0], e5 = q[16384], e6 = q[2 * 16384], e7 = q[3 * 16384];
        union { bf16x8 v; uint32_t u[4]; } bx;
        bx.u[0] = pkbf(e0, e1); bx.u[1] = pkbf(e2, e3);
        bx.u[2] = pkbf(e4, e5); bx.u[3] = pkbf(e6, e7);

        f32x4 h[4];
#pragma unroll
        for (int rt = 0; rt < 4; ++rt) {
            f32x4 acc = MFMA16(ain[rt], bx.v, bin[rt]);
#pragma unroll
            for (int r = 0; r < 4; ++r) acc[r] = fmaxf(acc[r], 0.f);
            h[rt] = acc;
        }
        union { bf16x8 v; uint32_t u[4]; } hb0, hb1;
        hb0.u[0] = pkbf(h[0][0], h[0][1]); hb0.u[1] = pkbf(h[0][2], h[0][3]);
        hb0.u[2] = pkbf(h[1][0], h[1][1]); hb0.u[3] = pkbf(h[1][2], h[1][3]);
        hb1.u[0] = pkbf(h[2][0], h[2][1]); hb1.u[1] = pkbf(h[2][2], h[2][3]);
        hb1.u[2] = pkbf(h[3][0], h[3][1]); hb1.u[3] = pkbf(h[3][2], h[3][3]);

        f32x4 m[4];
#pragma unroll
        for (int ot = 0; ot < 4; ++ot) {
            f32x4 acc = MFMA16(amid[ot][0], hb0.v, bmid[ot]);
            acc = MFMA16(amid[ot][1], hb1.v, acc);
#pragma unroll
            for (int r = 0; r < 4; ++r) acc[r] = fmaxf(acc[r], 0.f);
            m[ot] = acc;
        }
        union { bf16x8 v; uint32_t u[4]; } mb0, mb1;
        mb0.u[0] = pkbf(m[0][0], m[0][1]); mb0.u[1] = pkbf(m[0][2], m[0][3]);
        mb0.u[2] = pkbf(m[1][0], m[1][1]); mb0.u[3] = pkbf(m[1][2], m[1][3]);
        mb1.u[0] = pkbf(m[2][0], m[2][1]); mb1.u[1] = pkbf(m[2][2], m[2][3]);
        mb1.u[2] = pkbf(m[3][0], m[3][1]); mb1.u[3] = pkbf(m[3][2], m[3][3]);

#pragma unroll
        for (int ot = 0; ot < 2; ++ot) {
            f32x4 acc = MFMA16(ashort[ot], bx.v, bos[ot]);
            acc = MFMA16(aout[ot][0], mb0.v, acc);
            acc = MFMA16(aout[ot][1], mb1.v, acc);
            float* po = obase + (size_t)(16 * ot) * 16384 + px0;
            po[0]         = acc[0];
            po[16384]     = acc[1];
            po[2 * 16384] = acc[2];
            po[3 * 16384] = acc[3];
        }
    }
}

// ---------------------------------------------------------------------------
extern "C" void kernel_launch(void* const* d_in, const int* in_sizes, int n_in,
                              void* d_out, int out_size, void* d_ws, size_t ws_size,
                              hipStream_t stream)
{
    const float* x   = (const float*)d_in[0];
    const float* lat = (const float*)d_in[1];
    const float* w0  = (const float*)d_in[2];
    const float* b0  = (const float*)d_in[3];
    const float* w1a = (const float*)d_in[4];
    const float* b1a = (const float*)d_in[5];
    const float* w1b = (const float*)d_in[6];
    const float* b1b = (const float*)d_in[7];
    const float* w1s = (const float*)d_in[8];
    const float* b1s = (const float*)d_in[9];
    const float* w2a = (const float*)d_in[10];
    const float* b2a = (const float*)d_in[11];
    const float* w2b = (const float*)d_in[12];
    const float* b2b = (const float*)d_in[13];
    const float* w2s = (const float*)d_in[14];
    const float* b2s = (const float*)d_in[15];
    const float* wfa = (const float*)d_in[16];
    const float* bfa = (const float*)d_in[17];

    // intermediates in d_ws (~2.8 MB)
    float* ws  = (float*)d_ws;
    float* h0  = ws;               // 32*512
    float* t1  = ws + 16384;       // 32*1024
    float* h1  = ws + 49152;       // 32*512
    float* t2  = ws + 65536;       // 32*1024
    float* h2  = ws + 98304;       // 32*9408
    float* ksb = ws + 399360;      // 32*9408
    // wfa K-split partials live in d_out (25.3 MB < 64 MB); conv overwrites.
    float* pbuf = (float*)d_out;

    dim3 blk(256);

    // small chain: one-shot GEMMs, no partial round trips
    smallgemm<<<dim3(32), blk, 0, stream>>>(lat, w0, 512, nullptr, nullptr, 0,
                                            b0, nullptr, h0, 512, 0);
    smallgemm<<<dim3(64), blk, 0, stream>>>(h0, w1a, 512, nullptr, nullptr, 0,
                                            b1a, nullptr, t1, 1024, 1);
    smallgemm<<<dim3(32), blk, 0, stream>>>(h0, w1s, 512, t1, w1b, 1024,
                                            b1s, b1b, h1, 512, 0);
    smallgemm<<<dim3(64), blk, 0, stream>>>(h1, w2a, 512, nullptr, nullptr, 0,
                                            b2a, nullptr, t2, 1024, 1);
    // h2 = h1 @ w2s.T + b2s + t2 @ w2b.T + b2b   (588 blocks, 57.6 MB stream)
    smallgemm<<<dim3(588), blk, 0, stream>>>(h1, w2s, 512, t2, w2b, 1024,
                                             b2s, b2b, h2, KT, 0);
    // ks = h2 @ wfa.T + bfa   (ksplit 21 -> 777 blocks = 3.0/CU)
    gemm32_partial<<<dim3(37, 21), blk, 0, stream>>>(h2, wfa, KT, pbuf, KT, 21);
    reduce_bias<<<dim3((32 * KT + 255) / 256), blk, 0, stream>>>(pbuf, bfa, ksb, KT, 21);

    // MFMA conv chain
    conv_mfma<<<dim3(16, 32), blk, 0, stream>>>(x, ksb, (float*)d_out);
}